// Round 13
// baseline (49.866 us; speedup 1.0000x reference)
//
#include <hip/hip_runtime.h>
#include <hip/hip_bf16.h>
#include <stdint.h>

typedef short bf16x8 __attribute__((ext_vector_type(8)));
typedef float f32x4  __attribute__((ext_vector_type(4)));

#define B_   32
#define CIN  32
#define COUT 64
#define H_   128
#define W_   128
#define HW   (H_ * W_)
#define T_   2            // output rows per block
#define RROWS 4           // staged input rows = T_+2
#define PXW  130          // padded width
#define SCP  260          // block scratch row stride in words (16B-aligned; 4*260%32=16 -> 2-way banks)

static __device__ __forceinline__ ushort f2bf(float v) {
    __hip_bfloat16 h = __float2bfloat16(v);
    return __builtin_bit_cast(ushort, h);
}

// ---------------------------------------------------------------------------
// Weight pack: [Cout][Cin][3][3] fp32 -> bf16 A-fragment order
// Wp[tap][ocg][lane][j] = W[ocg*16 + (lane&15)][8*(lane>>4)+j][ky][kx]
// ---------------------------------------------------------------------------
__global__ void prep_w_kernel(const float* __restrict__ wt, ushort* __restrict__ Wp) {
    int p = blockIdx.x * blockDim.x + threadIdx.x;
    if (p >= COUT * CIN * 9) return;  // 18432
    int j    = p & 7;
    int lane = (p >> 3) & 63;
    int g    = (p >> 9) & 3;
    int tap  = p >> 11;
    int oc   = g * 16 + (lane & 15);
    int cin  = (lane >> 4) * 8 + j;
    int ky   = tap / 3;
    int kx   = tap % 3;
    Wp[p] = f2bf(wt[(((size_t)oc * CIN + cin) * 3 + ky) * 3 + kx]);
}

// ---------------------------------------------------------------------------
// R11 compute + BLOCK-LEVEL contiguous epilogue. Per g (16 oc): all 4 waves
// deposit acc into a block scratch tile [16 oc][256 px] (px = 2 rows x 128,
// contiguous in NCHW), barrier, then each store instruction writes ONE oc
// row = 1 KB fully sequential (8 cache lines) as nontemporal dwordx4.
// Theory: HBM write stream at fill-like contiguity -> fill-like (~7 TB/s)
// write rate; prior 256B-chunks-at-64KB-stride ran at ~3.1 TB/s.
// LDS = 33,280 (stage) + 16,640 (scratch) = 49,920 -> 3 blocks/CU.
// ---------------------------------------------------------------------------
__global__ __launch_bounds__(256, 3) void conv_fused_kernel(
    const float* __restrict__ in, const ushort* __restrict__ Wp,
    float* __restrict__ out) {
    __shared__ ushort lds[RROWS * PXW * 32];     // 33,280 B
    __shared__ float  scr[16 * SCP];             // 16,640 B block scratch

    int hw_blk  = blockIdx.x;
    int logical = (hw_blk & 7) * 256 + (hw_blk >> 3);   // grid = 2048 = 8*256
    int b   = logical >> 6;          // /64
    int h0  = (logical & 63) * T_;
    int tid = threadIdx.x;

    // ---- stage: thread = one (row, px) column, loop 32 channels ----
    for (int i = tid; i < RROWS * PXW; i += 256) {
        int r  = i / PXW;
        int px = i - r * PXW;
        int gy = h0 + r - 1;
        bf16x8 v[4];
        if (gy >= 0 && gy < H_ && px >= 1 && px <= W_) {
            const float* src = in + ((size_t)b * CIN * H_ + gy) * W_ + (px - 1);
#pragma unroll
            for (int q = 0; q < 4; ++q)
#pragma unroll
                for (int j = 0; j < 8; ++j)
                    v[q][j] = (short)f2bf(src[(size_t)(q * 8 + j) * HW]);
        } else {
#pragma unroll
            for (int q = 0; q < 4; ++q)
#pragma unroll
                for (int j = 0; j < 8; ++j)
                    v[q][j] = 0;
        }
        uint32_t base_byte = (uint32_t)i * 64;
        uint32_t sw = ((uint32_t)(px >> 1) & 3u) << 4;
#pragma unroll
        for (int q = 0; q < 4; ++q)
            *(bf16x8*)((char*)lds + base_byte + (((uint32_t)q << 4) ^ sw)) = v[q];
    }
    __syncthreads();

    // ---- compute: wave = (row = wid>>1, px half = wid&1), 64 oc x 64 px ----
    int wid  = tid >> 6;
    int lane = tid & 63;
    int llo  = lane & 15;
    int lhi  = lane >> 4;
    int row  = wid >> 1;            // 0..1
    int px0  = (wid & 1) * 64;

    f32x4 acc[4][4];
#pragma unroll
    for (int g = 0; g < 4; ++g)
#pragma unroll
        for (int nf = 0; nf < 4; ++nf) {
            acc[g][nf][0] = 0.f; acc[g][nf][1] = 0.f;
            acc[g][nf][2] = 0.f; acc[g][nf][3] = 0.f;
        }

#pragma unroll
    for (int tap = 0; tap < 9; ++tap) {
        int dy = tap / 3;
        int dx = tap % 3;
        int rbase = (row + dy) * PXW;
        bf16x8 Af[4];
#pragma unroll
        for (int g = 0; g < 4; ++g)
            Af[g] = *(const bf16x8*)(Wp + ((size_t)(tap * 4 + g) * 64 + lane) * 8);
#pragma unroll
        for (int nf = 0; nf < 4; ++nf) {
            int px = px0 + nf * 16 + llo + dx;
            uint32_t byte = (uint32_t)(rbase + px) * 64u +
                            (((uint32_t)lhi << 4) ^ ((((uint32_t)px >> 1) & 3u) << 4));
            bf16x8 Bf = *(const bf16x8*)((const char*)lds + byte);
#pragma unroll
            for (int g = 0; g < 4; ++g)
                acc[g][nf] = __builtin_amdgcn_mfma_f32_16x16x32_bf16(Af[g], Bf, acc[g][nf], 0, 0, 0);
        }
    }

    // ---- epilogue: block scratch [16 oc][256 px], 1KB-contiguous stores --
    // acc[g][nf][r] = (oc' = lhi*4+r, pxx = row*128 + px0 + nf*16 + llo).
    // After barrier: wave wid handles oc' = wid*4+k; lane l reads f32x4 at
    // pxx = l*4 -> 64 lanes = one full 1KB oc row -> nt dwordx4 store.
    int pxbase = row * 128 + px0;
    const float* oimg = out + (size_t)b * COUT * HW + (size_t)h0 * W_;
#pragma unroll
    for (int g = 0; g < 4; ++g) {
        if (g > 0) __syncthreads();      // prior g's reads done before overwrite
#pragma unroll
        for (int nf = 0; nf < 4; ++nf)
#pragma unroll
            for (int r = 0; r < 4; ++r)
                scr[(lhi * 4 + r) * SCP + pxbase + nf * 16 + llo] = acc[g][nf][r];
        __syncthreads();                 // all waves' deposits visible
#pragma unroll
        for (int k = 0; k < 4; ++k) {
            int ocp = wid * 4 + k;       // 0..15
            f32x4 vv = *(const f32x4*)(scr + ocp * SCP + lane * 4);
            float* dst = (float*)oimg + (size_t)(g * 16 + ocp) * HW + lane * 4;
#pragma unroll
            for (int m = 0; m < 4; ++m)
                __builtin_nontemporal_store(vv[m], dst + m);
        }
    }
}

// ---------------------------------------------------------------------------
// Fallback: naive fp32 direct conv (only if workspace is too small for Wp)
// ---------------------------------------------------------------------------
__global__ void conv_naive_kernel(const float* __restrict__ in,
                                  const float* __restrict__ wt,
                                  float* __restrict__ out) {
    int idx = blockIdx.x * blockDim.x + threadIdx.x;
    if (idx >= B_ * COUT * HW) return;
    int w  = idx & 127;
    int h  = (idx >> 7) & 127;
    int oc = (idx >> 14) & 63;
    int b  = idx >> 20;
    float s = 0.f;
    for (int c = 0; c < CIN; ++c)
        for (int ky = 0; ky < 3; ++ky) {
            int y = h + ky - 1;
            if ((unsigned)y >= (unsigned)H_) continue;
            for (int kx = 0; kx < 3; ++kx) {
                int x = w + kx - 1;
                if ((unsigned)x >= (unsigned)W_) continue;
                s += in[((size_t)(b * CIN + c) * H_ + y) * W_ + x] *
                     wt[(((size_t)oc * CIN + c) * 3 + ky) * 3 + kx];
            }
        }
    out[idx] = s;
}

extern "C" void kernel_launch(void* const* d_in, const int* in_sizes, int n_in,
                              void* d_out, int out_size, void* d_ws, size_t ws_size,
                              hipStream_t stream) {
    const float* in = (const float*)d_in[0];
    const float* wt = (const float*)d_in[1];
    float* out = (float*)d_out;

    size_t Wp_bytes = (size_t)COUT * CIN * 9 * 2;   // 36,864

    if (ws_size >= Wp_bytes) {
        ushort* Wp = (ushort*)d_ws;
        prep_w_kernel<<<(COUT * CIN * 9 + 255) / 256, 256, 0, stream>>>(wt, Wp);
        conv_fused_kernel<<<B_ * (H_ / T_), 256, 0, stream>>>(in, Wp, out);
    } else {
        int total = B_ * COUT * HW;
        conv_naive_kernel<<<(total + 255) / 256, 256, 0, stream>>>(in, wt, out);
    }
}